// Round 1
// baseline (200.495 us; speedup 1.0000x reference)
//
#include <hip/hip_runtime.h>

#define N_SRC 50000
#define N_DST 50000
#define E_CNT 800000
#define D 128
#define K 8

// d_ws layout (ints): [out_deg N_SRC][in_deg N_DST][neg_in N_DST][ptr N_DST]

__global__ void count_kernel(const int* __restrict__ src_idx,
                             const int* __restrict__ dst_idx,
                             const int* __restrict__ category,
                             int* __restrict__ out_deg,
                             int* __restrict__ in_deg,
                             int* __restrict__ neg_in) {
    int e = blockIdx.x * blockDim.x + threadIdx.x;
    if (e >= E_CNT) return;
    int s = src_idx[e];
    int dn = dst_idx[e];
    atomicAdd(&out_deg[s], 1);
    atomicAdd(&in_deg[dn], 1);
    if (category[s] == -1) atomicAdd(&neg_in[dn], 1);
}

__global__ void ptr_kernel(const int* __restrict__ dst_idx,
                           int* __restrict__ ptr) {
    int n = blockIdx.x * blockDim.x + threadIdx.x;
    if (n >= N_DST) return;
    // lower_bound of n in sorted dst_idx[0..E)
    int lo = 0, hi = E_CNT;
    while (lo < hi) {
        int mid = (lo + hi) >> 1;
        if (dst_idx[mid] < n) lo = mid + 1; else hi = mid;
    }
    ptr[n] = lo;
}

// one wave (64 lanes) per dst node; lane i owns columns [2i, 2i+1] (float2)
__global__ void gather_kernel(const float* __restrict__ h_src,
                              const float* __restrict__ unif,
                              const int* __restrict__ src_idx,
                              const int* __restrict__ out_deg,
                              const int* __restrict__ in_deg,
                              const int* __restrict__ neg_in,
                              const int* __restrict__ ptr,
                              float* __restrict__ out) {
    int gid = blockIdx.x * blockDim.x + threadIdx.x;
    int n = gid >> 6;           // wave id == dst node
    int lane = threadIdx.x & 63;
    if (n >= N_DST) return;

    int deg = in_deg[n];
    int p = ptr[n];
    bool use_full = (deg <= K) || (neg_in[n] > 0);

    const float2* h2 = (const float2*)h_src;
    float2 acc = make_float2(0.f, 0.f);

    if (use_full) {
        for (int i = 0; i < deg; ++i) {
            int s = src_idx[p + i];                       // broadcast load
            float norm = rsqrtf((float)max(out_deg[s], 1));
            float2 v = h2[(size_t)s * 64 + lane];         // coalesced 512B row
            acc.x += v.x * norm;
            acc.y += v.y * norm;
        }
    } else {
        // lane k (k<K) computes sampled edge id, matching reference float math:
        // off = floor(u * (float)deg); off = min(off, deg-1); eid = clip(p+off, 0, E-1)
        int s_k = 0;
        if (lane < K) {
            float u = unif[n * K + lane];
            int off = (int)floorf(u * (float)deg);
            if (off > deg - 1) off = deg - 1;
            if (off < 0) off = 0;
            int eid = p + off;
            if (eid < 0) eid = 0;
            if (eid > E_CNT - 1) eid = E_CNT - 1;
            s_k = src_idx[eid];
        }
        #pragma unroll
        for (int k = 0; k < K; ++k) {
            int s = __shfl(s_k, k, 64);
            float norm = rsqrtf((float)max(out_deg[s], 1));
            float2 v = h2[(size_t)s * 64 + lane];
            acc.x += v.x * norm;
            acc.y += v.y * norm;
        }
    }

    float in_norm = rsqrtf((float)max(deg, 1));
    float2 r;
    r.x = acc.x * in_norm;
    r.y = acc.y * in_norm;
    ((float2*)out)[(size_t)n * 64 + lane] = r;
}

extern "C" void kernel_launch(void* const* d_in, const int* in_sizes, int n_in,
                              void* d_out, int out_size, void* d_ws, size_t ws_size,
                              hipStream_t stream) {
    const float* h_src   = (const float*)d_in[0];
    // d_in[1] = h_dst (values unused by reference; only its shape matters)
    const float* unif    = (const float*)d_in[2];
    const int* src_idx   = (const int*)d_in[3];
    const int* dst_idx   = (const int*)d_in[4];
    const int* category  = (const int*)d_in[5];
    float* out = (float*)d_out;

    int* out_deg = (int*)d_ws;
    int* in_deg  = out_deg + N_SRC;
    int* neg_in  = in_deg + N_DST;
    int* ptr     = neg_in + N_DST;

    // zero the three accumulated arrays (ws is poisoned 0xAA before each run)
    hipMemsetAsync(out_deg, 0, (size_t)(N_SRC + 2 * N_DST) * sizeof(int), stream);

    {
        int threads = 256;
        int blocks = (E_CNT + threads - 1) / threads;
        count_kernel<<<blocks, threads, 0, stream>>>(src_idx, dst_idx, category,
                                                     out_deg, in_deg, neg_in);
    }
    {
        int threads = 256;
        int blocks = (N_DST + threads - 1) / threads;
        ptr_kernel<<<blocks, threads, 0, stream>>>(dst_idx, ptr);
    }
    {
        int threads = 256;                       // 4 waves/block
        long long total = (long long)N_DST * 64;
        int blocks = (int)((total + threads - 1) / threads);
        gather_kernel<<<blocks, threads, 0, stream>>>(h_src, unif, src_idx,
                                                      out_deg, in_deg, neg_in,
                                                      ptr, out);
    }
}

// Round 2
// 163.188 us; speedup vs baseline: 1.2286x; 1.2286x over previous
//
#include <hip/hip_runtime.h>

#define N_SRC 50000
#define N_DST 50000
#define E_CNT 800000
#define D 128
#define K 8

#define EDGE_BLOCKS ((E_CNT + 255) / 256)       // 3125
#define PTR_BLOCKS  ((N_DST + 1 + 255) / 256)   // 196

// d_ws layout (ints): [out_deg N_SRC][neg_in N_DST][ptr N_DST+1]

// Fused: blocks [0, EDGE_BLOCKS) do the out_deg histogram (+rare neg_in);
// blocks [EDGE_BLOCKS, EDGE_BLOCKS+PTR_BLOCKS) do the ptr binary searches.
// in_deg needs NO atomics: dst_idx is sorted, deg[n] = ptr[n+1]-ptr[n].
__global__ void count_ptr_kernel(const int* __restrict__ src_idx,
                                 const int* __restrict__ dst_idx,
                                 const int* __restrict__ category,
                                 int* __restrict__ out_deg,
                                 int* __restrict__ neg_in,
                                 int* __restrict__ ptr) {
    if (blockIdx.x < EDGE_BLOCKS) {
        int e = blockIdx.x * 256 + threadIdx.x;
        if (e >= E_CNT) return;
        int s = src_idx[e];
        atomicAdd(&out_deg[s], 1);
        if (category[s] == -1) {                 // ~never taken: skips dst_idx read
            atomicAdd(&neg_in[dst_idx[e]], 1);
        }
    } else {
        int n = (blockIdx.x - EDGE_BLOCKS) * 256 + threadIdx.x;
        if (n > N_DST) return;
        // lower_bound of n in sorted dst_idx[0..E); n==N_DST yields E
        int lo = 0, hi = E_CNT;
        while (lo < hi) {
            int mid = (lo + hi) >> 1;
            if (dst_idx[mid] < n) lo = mid + 1; else hi = mid;
        }
        ptr[n] = lo;
    }
}

// one wave (64 lanes) per dst node; lane i owns columns [2i, 2i+1] (float2)
__global__ void gather_kernel(const float* __restrict__ h_src,
                              const float* __restrict__ unif,
                              const int* __restrict__ src_idx,
                              const int* __restrict__ out_deg,
                              const int* __restrict__ neg_in,
                              const int* __restrict__ ptr,
                              float* __restrict__ out) {
    int gid = blockIdx.x * blockDim.x + threadIdx.x;
    int n = gid >> 6;           // wave id == dst node
    int lane = threadIdx.x & 63;
    if (n >= N_DST) return;

    int p = ptr[n];
    int deg = ptr[n + 1] - p;
    bool use_full = (deg <= K) || (neg_in[n] > 0);

    const float2* h2 = (const float2*)h_src;
    float2 acc = make_float2(0.f, 0.f);

    if (use_full) {
        for (int i = 0; i < deg; ++i) {
            int s = src_idx[p + i];                       // wave-uniform load
            float norm = rsqrtf((float)max(out_deg[s], 1));
            float2 v = h2[(size_t)s * 64 + lane];         // coalesced 512B row
            acc.x += v.x * norm;
            acc.y += v.y * norm;
        }
    } else {
        // lane k (k<K) computes sampled edge id, matching reference float math:
        // off = floor(u * (float)deg); off = min(off, deg-1); eid = clip(p+off, 0, E-1)
        int s_k = 0;
        if (lane < K) {
            float u = unif[n * K + lane];
            int off = (int)floorf(u * (float)deg);
            if (off > deg - 1) off = deg - 1;
            if (off < 0) off = 0;
            int eid = p + off;
            if (eid < 0) eid = 0;
            if (eid > E_CNT - 1) eid = E_CNT - 1;
            s_k = src_idx[eid];
        }
        #pragma unroll
        for (int k = 0; k < K; ++k) {
            int s = __shfl(s_k, k, 64);
            float norm = rsqrtf((float)max(out_deg[s], 1));
            float2 v = h2[(size_t)s * 64 + lane];
            acc.x += v.x * norm;
            acc.y += v.y * norm;
        }
    }

    float in_norm = rsqrtf((float)max(deg, 1));
    float2 r;
    r.x = acc.x * in_norm;
    r.y = acc.y * in_norm;
    ((float2*)out)[(size_t)n * 64 + lane] = r;
}

extern "C" void kernel_launch(void* const* d_in, const int* in_sizes, int n_in,
                              void* d_out, int out_size, void* d_ws, size_t ws_size,
                              hipStream_t stream) {
    const float* h_src   = (const float*)d_in[0];
    // d_in[1] = h_dst (values unused by the reference)
    const float* unif    = (const float*)d_in[2];
    const int* src_idx   = (const int*)d_in[3];
    const int* dst_idx   = (const int*)d_in[4];
    const int* category  = (const int*)d_in[5];
    float* out = (float*)d_out;

    int* out_deg = (int*)d_ws;
    int* neg_in  = out_deg + N_SRC;
    int* ptr     = neg_in + N_DST;

    // zero out_deg + neg_in (ws is poisoned 0xAA before each run)
    hipMemsetAsync(out_deg, 0, (size_t)(N_SRC + N_DST) * sizeof(int), stream);

    count_ptr_kernel<<<EDGE_BLOCKS + PTR_BLOCKS, 256, 0, stream>>>(
        src_idx, dst_idx, category, out_deg, neg_in, ptr);

    {
        int threads = 256;                       // 4 waves/block
        long long total = (long long)N_DST * 64;
        int blocks = (int)((total + threads - 1) / threads);
        gather_kernel<<<blocks, threads, 0, stream>>>(h_src, unif, src_idx,
                                                      out_deg, neg_in,
                                                      ptr, out);
    }
}

// Round 3
// 162.540 us; speedup vs baseline: 1.2335x; 1.0040x over previous
//
#include <hip/hip_runtime.h>

#define N_SRC 50000
#define N_DST 50000
#define E_CNT 800000
#define D 128
#define K 8
#define NSHADOW 8

#define CNT_THREADS (E_CNT / 4)                    // 200000, 4 edges/thread
#define CNT_BLOCKS ((CNT_THREADS + 255) / 256)     // 782
#define PTR_BLOCKS ((N_DST + 1 + 255) / 256)       // 196

// d_ws layout (ints):
//   [shadow 8*N_SRC][neg_in N_DST][ptr N_DST+1][out_norm(float) N_SRC]

__device__ __forceinline__ int xcc_id() {
    int x;
    asm("s_getreg_b32 %0, hwreg(HW_REG_XCC_ID)" : "=s"(x));
    return x & (NSHADOW - 1);
}

// XCD-local (TCC-resident) atomic add: no sc1 bit -> executes in this XCD's L2.
// Safe because each shadow histogram is touched by exactly one XCD.
__device__ __forceinline__ void atomic_add_xcd(int* p, int v) {
    asm volatile("global_atomic_add %0, %1, off" :: "v"(p), "v"(v) : "memory");
}

// Fused: blocks [0, CNT_BLOCKS) histogram src_idx into per-XCD shadows;
// blocks [CNT_BLOCKS, +PTR_BLOCKS) binary-search ptr[] in sorted dst_idx.
__global__ void count_ptr_kernel(const int* __restrict__ src_idx,
                                 const int* __restrict__ dst_idx,
                                 const int* __restrict__ category,
                                 int* __restrict__ shadow,
                                 int* __restrict__ neg_in,
                                 int* __restrict__ ptr) {
    if (blockIdx.x < CNT_BLOCKS) {
        int t = blockIdx.x * 256 + threadIdx.x;
        if (t >= CNT_THREADS) return;
        int* sh = shadow + (size_t)xcc_id() * N_SRC;
        int4 s = ((const int4*)src_idx)[t];
        atomic_add_xcd(&sh[s.x], 1);
        atomic_add_xcd(&sh[s.y], 1);
        atomic_add_xcd(&sh[s.z], 1);
        atomic_add_xcd(&sh[s.w], 1);
        // rare escape hatch: category == -1 (device-scope, ~never fires)
        if (category[s.x] == -1) atomicAdd(&neg_in[dst_idx[4 * t + 0]], 1);
        if (category[s.y] == -1) atomicAdd(&neg_in[dst_idx[4 * t + 1]], 1);
        if (category[s.z] == -1) atomicAdd(&neg_in[dst_idx[4 * t + 2]], 1);
        if (category[s.w] == -1) atomicAdd(&neg_in[dst_idx[4 * t + 3]], 1);
    } else {
        int n = (blockIdx.x - CNT_BLOCKS) * 256 + threadIdx.x;
        if (n > N_DST) return;
        // lower_bound of n in sorted dst_idx[0..E); n==N_DST yields E
        int lo = 0, hi = E_CNT;
        while (lo < hi) {
            int mid = (lo + hi) >> 1;
            if (dst_idx[mid] < n) lo = mid + 1; else hi = mid;
        }
        ptr[n] = lo;
    }
}

// Sum the 8 shadows -> out_norm[s] = rsqrt(max(deg,1))
__global__ void reduce_norm_kernel(const int* __restrict__ shadow,
                                   float* __restrict__ out_norm) {
    int n = blockIdx.x * blockDim.x + threadIdx.x;
    if (n >= N_SRC) return;
    int d = 0;
    #pragma unroll
    for (int x = 0; x < NSHADOW; ++x) d += shadow[(size_t)x * N_SRC + n];
    out_norm[n] = rsqrtf((float)max(d, 1));
}

// one wave (64 lanes) per dst node; lane i owns columns [2i, 2i+1] (float2)
__global__ void gather_kernel(const float* __restrict__ h_src,
                              const float* __restrict__ unif,
                              const int* __restrict__ src_idx,
                              const float* __restrict__ out_norm,
                              const int* __restrict__ neg_in,
                              const int* __restrict__ ptr,
                              float* __restrict__ out) {
    int gid = blockIdx.x * blockDim.x + threadIdx.x;
    int n = gid >> 6;           // wave id == dst node
    int lane = threadIdx.x & 63;
    if (n >= N_DST) return;

    int p = ptr[n];
    int deg = ptr[n + 1] - p;
    bool use_full = (deg <= K) || (neg_in[n] > 0);

    const float2* h2 = (const float2*)h_src;
    float2 acc = make_float2(0.f, 0.f);

    if (use_full) {
        for (int i = 0; i < deg; ++i) {
            int s = src_idx[p + i];                       // wave-uniform load
            float norm = out_norm[s];
            float2 v = h2[(size_t)s * 64 + lane];         // coalesced 512B row
            acc.x += v.x * norm;
            acc.y += v.y * norm;
        }
    } else {
        // lane k (k<K) computes sampled edge id, matching reference float math
        int s_k = 0;
        if (lane < K) {
            float u = unif[n * K + lane];
            int off = (int)floorf(u * (float)deg);
            if (off > deg - 1) off = deg - 1;
            if (off < 0) off = 0;
            int eid = p + off;
            if (eid < 0) eid = 0;
            if (eid > E_CNT - 1) eid = E_CNT - 1;
            s_k = src_idx[eid];
        }
        #pragma unroll
        for (int k = 0; k < K; ++k) {
            int s = __shfl(s_k, k, 64);
            float norm = out_norm[s];
            float2 v = h2[(size_t)s * 64 + lane];
            acc.x += v.x * norm;
            acc.y += v.y * norm;
        }
    }

    float in_norm = rsqrtf((float)max(deg, 1));
    float2 r;
    r.x = acc.x * in_norm;
    r.y = acc.y * in_norm;
    ((float2*)out)[(size_t)n * 64 + lane] = r;
}

extern "C" void kernel_launch(void* const* d_in, const int* in_sizes, int n_in,
                              void* d_out, int out_size, void* d_ws, size_t ws_size,
                              hipStream_t stream) {
    const float* h_src   = (const float*)d_in[0];
    // d_in[1] = h_dst (values unused by the reference)
    const float* unif    = (const float*)d_in[2];
    const int* src_idx   = (const int*)d_in[3];
    const int* dst_idx   = (const int*)d_in[4];
    const int* category  = (const int*)d_in[5];
    float* out = (float*)d_out;

    int* shadow    = (int*)d_ws;
    int* neg_in    = shadow + (size_t)NSHADOW * N_SRC;
    int* ptr       = neg_in + N_DST;
    float* out_norm = (float*)(ptr + N_DST + 1);

    // zero shadows + neg_in (ws is poisoned 0xAA before each run)
    hipMemsetAsync(shadow, 0, ((size_t)NSHADOW * N_SRC + N_DST) * sizeof(int), stream);

    count_ptr_kernel<<<CNT_BLOCKS + PTR_BLOCKS, 256, 0, stream>>>(
        src_idx, dst_idx, category, shadow, neg_in, ptr);

    reduce_norm_kernel<<<(N_SRC + 255) / 256, 256, 0, stream>>>(shadow, out_norm);

    {
        int threads = 256;                       // 4 waves/block
        long long total = (long long)N_DST * 64;
        int blocks = (int)((total + threads - 1) / threads);
        gather_kernel<<<blocks, threads, 0, stream>>>(h_src, unif, src_idx,
                                                      out_norm, neg_in,
                                                      ptr, out);
    }
}

// Round 4
// 145.626 us; speedup vs baseline: 1.3768x; 1.1161x over previous
//
#include <hip/hip_runtime.h>

#define N_SRC 50000
#define N_DST 50000
#define E_CNT 800000
#define D 128
#define K 8

#define HIST_BLOCKS 64
#define HIST_THREADS 512
#define PTR_BLOCKS ((N_DST + 1 + HIST_THREADS - 1) / HIST_THREADS)  // 98
#define HALF 25000               // src nodes per pass
#define HWORDS (HALF / 2)        // 12500 packed words = 50 KB LDS
#define NCHUNK (E_CNT / 4)       // 200000 int4 chunks

// d_ws layout:
//   [slab HIST_BLOCKS*N_SRC int][neg_in N_DST int][ptr N_DST+1 int][out_norm N_SRC float]

// Fused: blocks [0, HIST_BLOCKS) do an LDS-privatized histogram of src_idx
// (packed 2 nodes/word, 2 range passes) and dump per-block slabs — NO global
// atomics. Blocks [HIST_BLOCKS, +PTR_BLOCKS) binary-search ptr[] (dst_idx is
// sorted, so in_deg[n] = ptr[n+1]-ptr[n] — also atomic-free).
__global__ __launch_bounds__(HIST_THREADS)
void count_ptr_kernel(const int* __restrict__ src_idx,
                      const int* __restrict__ dst_idx,
                      const int* __restrict__ category,
                      int* __restrict__ slab,
                      int* __restrict__ neg_in,
                      int* __restrict__ ptr) {
    if (blockIdx.x < HIST_BLOCKS) {
        __shared__ int hist[HWORDS];
        const int4* s4 = (const int4*)src_idx;
        int* myslab = slab + (size_t)blockIdx.x * N_SRC;

        for (int pass = 0; pass < 2; ++pass) {
            int base = pass * HALF;
            for (int j = threadIdx.x; j < HWORDS; j += HIST_THREADS) hist[j] = 0;
            __syncthreads();

            for (int c = blockIdx.x * HIST_THREADS + threadIdx.x; c < NCHUNK;
                 c += HIST_BLOCKS * HIST_THREADS) {
                int4 s = s4[c];
                int r;
                // packed counter: word r>>1, low half = even node, high = odd.
                // per-block count <= 12500 < 2^16 -> no cross-half carry.
                r = s.x - base; if ((unsigned)r < HALF) atomicAdd(&hist[r >> 1], 1 << ((r & 1) * 16));
                r = s.y - base; if ((unsigned)r < HALF) atomicAdd(&hist[r >> 1], 1 << ((r & 1) * 16));
                r = s.z - base; if ((unsigned)r < HALF) atomicAdd(&hist[r >> 1], 1 << ((r & 1) * 16));
                r = s.w - base; if ((unsigned)r < HALF) atomicAdd(&hist[r >> 1], 1 << ((r & 1) * 16));
                if (pass == 0) {   // rare escape hatch, once per edge
                    if (category[s.x] == -1) atomicAdd(&neg_in[dst_idx[4 * c + 0]], 1);
                    if (category[s.y] == -1) atomicAdd(&neg_in[dst_idx[4 * c + 1]], 1);
                    if (category[s.z] == -1) atomicAdd(&neg_in[dst_idx[4 * c + 2]], 1);
                    if (category[s.w] == -1) atomicAdd(&neg_in[dst_idx[4 * c + 3]], 1);
                }
            }
            __syncthreads();

            // dump: word j -> counts for nodes base+2j, base+2j+1 (int2, coalesced)
            for (int j = threadIdx.x; j < HWORDS; j += HIST_THREADS) {
                unsigned w = (unsigned)hist[j];
                ((int2*)(myslab + base))[j] = make_int2((int)(w & 0xffffu), (int)(w >> 16));
            }
            __syncthreads();
        }
    } else {
        int n = (blockIdx.x - HIST_BLOCKS) * HIST_THREADS + threadIdx.x;
        if (n > N_DST) return;
        // lower_bound of n in sorted dst_idx[0..E); n==N_DST yields E
        int lo = 0, hi = E_CNT;
        while (lo < hi) {
            int mid = (lo + hi) >> 1;
            if (dst_idx[mid] < n) lo = mid + 1; else hi = mid;
        }
        ptr[n] = lo;
    }
}

// Sum the per-block slabs -> out_norm[s] = rsqrt(max(out_deg,1))
__global__ void reduce_norm_kernel(const int* __restrict__ slab,
                                   float* __restrict__ out_norm) {
    int n = blockIdx.x * blockDim.x + threadIdx.x;
    if (n >= N_SRC) return;
    int d = 0;
    #pragma unroll
    for (int b = 0; b < HIST_BLOCKS; ++b) d += slab[(size_t)b * N_SRC + n];
    out_norm[n] = rsqrtf((float)max(d, 1));
}

// one wave (64 lanes) per dst node; lane i owns columns [2i, 2i+1] (float2)
__global__ void gather_kernel(const float* __restrict__ h_src,
                              const float* __restrict__ unif,
                              const int* __restrict__ src_idx,
                              const float* __restrict__ out_norm,
                              const int* __restrict__ neg_in,
                              const int* __restrict__ ptr,
                              float* __restrict__ out) {
    int gid = blockIdx.x * blockDim.x + threadIdx.x;
    int n = gid >> 6;           // wave id == dst node
    int lane = threadIdx.x & 63;
    if (n >= N_DST) return;

    int p = ptr[n];
    int deg = ptr[n + 1] - p;
    bool use_full = (deg <= K) || (neg_in[n] > 0);

    const float2* h2 = (const float2*)h_src;
    float2 acc = make_float2(0.f, 0.f);

    if (use_full) {
        for (int i = 0; i < deg; ++i) {
            int s = src_idx[p + i];                       // wave-uniform load
            float norm = out_norm[s];
            float2 v = h2[(size_t)s * 64 + lane];         // coalesced 512B row
            acc.x += v.x * norm;
            acc.y += v.y * norm;
        }
    } else {
        // lane k (k<K) computes sampled edge id, matching reference float math
        int s_k = 0;
        if (lane < K) {
            float u = unif[n * K + lane];
            int off = (int)floorf(u * (float)deg);
            if (off > deg - 1) off = deg - 1;
            if (off < 0) off = 0;
            int eid = p + off;
            if (eid < 0) eid = 0;
            if (eid > E_CNT - 1) eid = E_CNT - 1;
            s_k = src_idx[eid];
        }
        #pragma unroll
        for (int k = 0; k < K; ++k) {
            int s = __shfl(s_k, k, 64);
            float norm = out_norm[s];
            float2 v = h2[(size_t)s * 64 + lane];
            acc.x += v.x * norm;
            acc.y += v.y * norm;
        }
    }

    float in_norm = rsqrtf((float)max(deg, 1));
    float2 r;
    r.x = acc.x * in_norm;
    r.y = acc.y * in_norm;
    ((float2*)out)[(size_t)n * 64 + lane] = r;
}

extern "C" void kernel_launch(void* const* d_in, const int* in_sizes, int n_in,
                              void* d_out, int out_size, void* d_ws, size_t ws_size,
                              hipStream_t stream) {
    const float* h_src   = (const float*)d_in[0];
    // d_in[1] = h_dst (values unused by the reference)
    const float* unif    = (const float*)d_in[2];
    const int* src_idx   = (const int*)d_in[3];
    const int* dst_idx   = (const int*)d_in[4];
    const int* category  = (const int*)d_in[5];
    float* out = (float*)d_out;

    int* slab      = (int*)d_ws;
    int* neg_in    = slab + (size_t)HIST_BLOCKS * N_SRC;
    int* ptr       = neg_in + N_DST;
    float* out_norm = (float*)(ptr + N_DST + 1);

    // zero neg_in only (slabs are fully overwritten; LDS zeroed in-kernel)
    hipMemsetAsync(neg_in, 0, (size_t)N_DST * sizeof(int), stream);

    count_ptr_kernel<<<HIST_BLOCKS + PTR_BLOCKS, HIST_THREADS, 0, stream>>>(
        src_idx, dst_idx, category, slab, neg_in, ptr);

    reduce_norm_kernel<<<(N_SRC + 255) / 256, 256, 0, stream>>>(slab, out_norm);

    {
        int threads = 256;                       // 4 waves/block
        long long total = (long long)N_DST * 64;
        int blocks = (int)((total + threads - 1) / threads);
        gather_kernel<<<blocks, threads, 0, stream>>>(h_src, unif, src_idx,
                                                      out_norm, neg_in,
                                                      ptr, out);
    }
}

// Round 5
// 142.922 us; speedup vs baseline: 1.4028x; 1.0189x over previous
//
#include <hip/hip_runtime.h>

#define N_SRC 50000
#define N_DST 50000
#define E_CNT 800000
#define D 128
#define K 8

#define HIST_BLOCKS 64
#define HIST_THREADS 512
#define PTR_BLOCKS ((N_DST + 1 + HIST_THREADS - 1) / HIST_THREADS)  // 98
#define HALF 25000               // src nodes per pass
#define HWORDS (HALF / 2)        // 12500 packed words = 50 KB LDS
#define NCHUNK (E_CNT / 4)       // 200000 int4 chunks

// d_ws layout:
//   [slab HIST_BLOCKS*N_SRC int][neg_in N_DST int][ptr N_DST+1 int][out_norm N_SRC float]

// Fused: blocks [0, HIST_BLOCKS) do an LDS-privatized histogram of src_idx
// (packed 2 nodes/word, 2 range passes) and dump per-block slabs — NO global
// atomics. Blocks [HIST_BLOCKS, +PTR_BLOCKS) binary-search ptr[] (dst_idx is
// sorted, so in_deg[n] = ptr[n+1]-ptr[n] — also atomic-free).
__global__ __launch_bounds__(HIST_THREADS)
void count_ptr_kernel(const int* __restrict__ src_idx,
                      const int* __restrict__ dst_idx,
                      const int* __restrict__ category,
                      int* __restrict__ slab,
                      int* __restrict__ neg_in,
                      int* __restrict__ ptr) {
    if (blockIdx.x < HIST_BLOCKS) {
        __shared__ int hist[HWORDS];
        const int4* s4 = (const int4*)src_idx;
        int* myslab = slab + (size_t)blockIdx.x * N_SRC;

        for (int pass = 0; pass < 2; ++pass) {
            int base = pass * HALF;
            for (int j = threadIdx.x; j < HWORDS; j += HIST_THREADS) hist[j] = 0;
            __syncthreads();

            for (int c = blockIdx.x * HIST_THREADS + threadIdx.x; c < NCHUNK;
                 c += HIST_BLOCKS * HIST_THREADS) {
                int4 s = s4[c];
                int r;
                // packed counter: word r>>1, low half = even node, high = odd.
                // per-block count <= 12500 < 2^16 -> no cross-half carry.
                r = s.x - base; if ((unsigned)r < HALF) atomicAdd(&hist[r >> 1], 1 << ((r & 1) * 16));
                r = s.y - base; if ((unsigned)r < HALF) atomicAdd(&hist[r >> 1], 1 << ((r & 1) * 16));
                r = s.z - base; if ((unsigned)r < HALF) atomicAdd(&hist[r >> 1], 1 << ((r & 1) * 16));
                r = s.w - base; if ((unsigned)r < HALF) atomicAdd(&hist[r >> 1], 1 << ((r & 1) * 16));
                if (pass == 0) {   // rare escape hatch, once per edge
                    if (category[s.x] == -1) atomicAdd(&neg_in[dst_idx[4 * c + 0]], 1);
                    if (category[s.y] == -1) atomicAdd(&neg_in[dst_idx[4 * c + 1]], 1);
                    if (category[s.z] == -1) atomicAdd(&neg_in[dst_idx[4 * c + 2]], 1);
                    if (category[s.w] == -1) atomicAdd(&neg_in[dst_idx[4 * c + 3]], 1);
                }
            }
            __syncthreads();

            // dump: word j -> counts for nodes base+2j, base+2j+1 (int2, coalesced)
            for (int j = threadIdx.x; j < HWORDS; j += HIST_THREADS) {
                unsigned w = (unsigned)hist[j];
                ((int2*)(myslab + base))[j] = make_int2((int)(w & 0xffffu), (int)(w >> 16));
            }
            __syncthreads();
        }
    } else {
        int n = (blockIdx.x - HIST_BLOCKS) * HIST_THREADS + threadIdx.x;
        if (n > N_DST) return;
        // lower_bound of n in sorted dst_idx[0..E); n==N_DST yields E
        int lo = 0, hi = E_CNT;
        while (lo < hi) {
            int mid = (lo + hi) >> 1;
            if (dst_idx[mid] < n) lo = mid + 1; else hi = mid;
        }
        ptr[n] = lo;
    }
}

// Sum the per-block slabs -> out_norm[s] = rsqrt(max(out_deg,1))
__global__ void reduce_norm_kernel(const int* __restrict__ slab,
                                   float* __restrict__ out_norm) {
    int n = blockIdx.x * blockDim.x + threadIdx.x;
    if (n >= N_SRC) return;
    int d = 0;
    #pragma unroll
    for (int b = 0; b < HIST_BLOCKS; ++b) d += slab[(size_t)b * N_SRC + n];
    out_norm[n] = rsqrtf((float)max(d, 1));
}

// TWO dst nodes per wave: lanes 0-31 -> node 2w, lanes 32-63 -> node 2w+1.
// Each lane owns a float4 (16 B x 32 lanes = one full 512 B feature row).
__global__ void gather_kernel(const float* __restrict__ h_src,
                              const float* __restrict__ unif,
                              const int* __restrict__ src_idx,
                              const float* __restrict__ out_norm,
                              const int* __restrict__ neg_in,
                              const int* __restrict__ ptr,
                              float* __restrict__ out) {
    int wave = (blockIdx.x * blockDim.x + threadIdx.x) >> 6;
    int lane = threadIdx.x & 63;
    int sub = lane & 31;                 // lane within half-wave
    int n = wave * 2 + (lane >> 5);      // this half's dst node
    if (n >= N_DST) return;

    int p = ptr[n];
    int deg = ptr[n + 1] - p;
    bool use_full = (deg <= K) || (neg_in[n] > 0);

    const float4* h4 = (const float4*)h_src;
    float4 acc = make_float4(0.f, 0.f, 0.f, 0.f);

    if (use_full) {
        for (int i = 0; i < deg; ++i) {
            int s = src_idx[p + i];                  // uniform per half-wave
            float norm = out_norm[s];
            float4 v = h4[(size_t)s * 32 + sub];     // coalesced 512B row / half
            acc.x += v.x * norm;
            acc.y += v.y * norm;
            acc.z += v.z * norm;
            acc.w += v.w * norm;
        }
    } else {
        // lanes sub<K of each half compute this node's sampled edge ids,
        // matching reference float math:
        // off = floor(u*(float)deg); off=min(off,deg-1); eid=clip(p+off,0,E-1)
        int s_k = 0;
        if (sub < K) {
            float u = unif[n * K + sub];
            int off = (int)floorf(u * (float)deg);
            if (off > deg - 1) off = deg - 1;
            if (off < 0) off = 0;
            int eid = p + off;
            if (eid < 0) eid = 0;
            if (eid > E_CNT - 1) eid = E_CNT - 1;
            s_k = src_idx[eid];
        }
        #pragma unroll
        for (int k = 0; k < K; ++k) {
            int s = __shfl(s_k, (lane & 32) + k, 64);   // stays in active half
            float norm = out_norm[s];
            float4 v = h4[(size_t)s * 32 + sub];
            acc.x += v.x * norm;
            acc.y += v.y * norm;
            acc.z += v.z * norm;
            acc.w += v.w * norm;
        }
    }

    float in_norm = rsqrtf((float)max(deg, 1));
    float4 r;
    r.x = acc.x * in_norm;
    r.y = acc.y * in_norm;
    r.z = acc.z * in_norm;
    r.w = acc.w * in_norm;
    ((float4*)out)[(size_t)n * 32 + sub] = r;
}

extern "C" void kernel_launch(void* const* d_in, const int* in_sizes, int n_in,
                              void* d_out, int out_size, void* d_ws, size_t ws_size,
                              hipStream_t stream) {
    const float* h_src   = (const float*)d_in[0];
    // d_in[1] = h_dst (values unused by the reference)
    const float* unif    = (const float*)d_in[2];
    const int* src_idx   = (const int*)d_in[3];
    const int* dst_idx   = (const int*)d_in[4];
    const int* category  = (const int*)d_in[5];
    float* out = (float*)d_out;

    int* slab      = (int*)d_ws;
    int* neg_in    = slab + (size_t)HIST_BLOCKS * N_SRC;
    int* ptr       = neg_in + N_DST;
    float* out_norm = (float*)(ptr + N_DST + 1);

    // zero neg_in only (slabs are fully overwritten; LDS zeroed in-kernel)
    hipMemsetAsync(neg_in, 0, (size_t)N_DST * sizeof(int), stream);

    count_ptr_kernel<<<HIST_BLOCKS + PTR_BLOCKS, HIST_THREADS, 0, stream>>>(
        src_idx, dst_idx, category, slab, neg_in, ptr);

    reduce_norm_kernel<<<(N_SRC + 255) / 256, 256, 0, stream>>>(slab, out_norm);

    {
        // 2 nodes/wave, 4 waves/block -> 8 nodes/block; 50000/8 = 6250 blocks
        int threads = 256;
        int blocks = (N_DST + 7) / 8;
        gather_kernel<<<blocks, threads, 0, stream>>>(h_src, unif, src_idx,
                                                      out_norm, neg_in,
                                                      ptr, out);
    }
}